// Round 18
// baseline (495.673 us; speedup 1.0000x reference)
//
#include <hip/hip_runtime.h>
#include <hip/hip_bf16.h>

// Problem constants
#define S_LEN 1024
#define HID   4096
#define NH    32
#define NKV   8
#define HD    128
#define MIN_IDX 4
#define AO_COLS 4096        // NH*HD
#define HEAD_STRIDE 131072  // S_LEN*HD
#define P32_SPLIT 4194304   // f32 elems in `out` before spilling into AO

typedef __attribute__((ext_vector_type(8))) short short8;
typedef __attribute__((ext_vector_type(4))) float f32x4;

__device__ __forceinline__ unsigned short f2bf(float f) {
  union { float f; unsigned u; } v; v.f = f;
  unsigned r = v.u + 0x7FFFu + ((v.u >> 16) & 1u);   // RNE
  return (unsigned short)(r >> 16);
}
__device__ __forceinline__ float bf2f(unsigned short h) {
  union { unsigned u; float f; } v; v.u = ((unsigned)h) << 16;
  return v.f;
}
__device__ __forceinline__ unsigned pk2(float a, float b) {
  union { __hip_bfloat162 h; unsigned u; } c;
  c.h = __float22bfloat162_rn(make_float2(a, b));    // v_cvt_pk_bf16_f32
  return c.u;
}
__device__ __forceinline__ short8 pack8(float4 a, float4 b) {
  union { short8 s; unsigned u[4]; } r;
  r.u[0] = pk2(a.x, a.y); r.u[1] = pk2(a.z, a.w);
  r.u[2] = pk2(b.x, b.y); r.u[3] = pk2(b.z, b.w);
  return r.s;
}
// float -> order-preserving uint, and inverse
__device__ __forceinline__ unsigned ordf(float f) {
  union { float f; int i; } v; v.f = f;
  return (unsigned)(v.i ^ ((v.i >> 31) | 0x80000000));
}
__device__ __forceinline__ float iordf(unsigned u) {
  union { int i; float f; } v;
  v.i = (u & 0x80000000u) ? (int)(u ^ 0x80000000u) : (int)~u;
  return v.f;
}
__device__ __forceinline__ float wave_sum_f(float v) {
  #pragma unroll
  for (int m = 32; m >= 1; m >>= 1) v += __shfl_xor(v, m);
  return v;
}
__device__ __forceinline__ unsigned wave_max_u(unsigned v) {
  #pragma unroll
  for (int m = 32; m >= 1; m >>= 1) { unsigned o = __shfl_xor(v, m); v = o > v ? o : v; }
  return v;
}
// wave-local LDS fence: hist[w] is wave-private, so no block barrier needed.
// Wait lgkmcnt(0) only (vmcnt=63, expcnt=7 -> don't wait): imm = 0xC07F.
__device__ __forceinline__ void wave_lds_fence() {
  __builtin_amdgcn_s_waitcnt(0xC07F);
  __builtin_amdgcn_wave_barrier();      // stop compiler reordering
}
// async global->LDS, 16 B per lane. LDS dest: wave-uniform base + lane*16.
__device__ __forceinline__ void gload_lds16(const unsigned short* g, unsigned short* l) {
  auto gp = (const __attribute__((address_space(1))) unsigned*)g;
  auto lp = (__attribute__((address_space(3))) unsigned*)(unsigned)(unsigned long long)l;
  __builtin_amdgcn_global_load_lds(gp, lp, 16, 0, 0);
}
// P32 f32 buffer split across out (4,194,304 f32) then AO region
__device__ __forceinline__ float* p32ptr(float* outp, float* aof, size_t e) {
  return (e < (size_t)P32_SPLIT) ? (outp + e) : (aof + (e - P32_SPLIT));
}

// ---------------------------------------------------------------------------
// Kernel 0: fused convert of X, Wq, Wk, Wv (14336 blocks, 2048 elem/blk).
// ---------------------------------------------------------------------------
__global__ __launch_bounds__(256) void cvt4_k(
    const float* __restrict__ s0, const float* __restrict__ s1,
    const float* __restrict__ s2, const float* __restrict__ s3,
    unsigned short* __restrict__ d0, unsigned short* __restrict__ d1)
{
  const int b = blockIdx.x;
  const float* src; unsigned short* dst; int rb;
  if (b < 2048)       { src = s0; dst = d0;            rb = b; }
  else if (b < 10240) { src = s1; dst = d1;            rb = b - 2048; }
  else if (b < 12288) { src = s2; dst = d1 + 16777216; rb = b - 10240; }
  else                { src = s3; dst = d1 + 20971520; rb = b - 12288; }
  const size_t i = ((size_t)rb * 256 + threadIdx.x) * 8;
  float4 a = *(const float4*)(src + i);
  float4 c = *(const float4*)(src + i + 4);
  *(short8*)(dst + i) = pack8(a, c);
}

// ---------------------------------------------------------------------------
// Kernel 1: QKV projection, 128x128 tiles, SPLIT-K for Q|K.
// Grid (88, 8) = 704 blocks:
//   x in [0,8):  V tiles (nt = 40+x), FULL K (128 tiles), transposed bf16
//                store to Vt — dispatched FIRST (heavy blocks early).
//   x in [8,88): Q|K tiles, nt = (x-8)>>1, K-half z = (x-8)&1 (64 tiles),
//                f32 atomicAdd into P32 (= out ++ first 4MB of AO).
// Per-CU work: ~192 tile-units (vs 256 at 1.5 blk/CU before), ~2.75 blk/CU.
// Depth-2 pipeline: 3-buffer LDS, counted s_waitcnt vmcnt(4), 1 barrier/iter.
// ---------------------------------------------------------------------------
__global__ __launch_bounds__(256) void gemm_qkv_k(
    const unsigned short* __restrict__ Xb, const unsigned short* __restrict__ Wb,
    float* __restrict__ P32a, float* __restrict__ P32b,
    unsigned short* __restrict__ Vt)
{
  __shared__ unsigned short As[3][128 * 32];
  __shared__ unsigned short Bs[3][128 * 32];
  const int x = blockIdx.x;
  const bool isV = x < 8;
  int nt, kbase, ntiles;
  if (isV) { nt = 40 + x;            kbase = 0;                 ntiles = 128; }
  else     { const int idx = x - 8;  nt = idx >> 1;
             kbase = (idx & 1) * 2048;                          ntiles = 64;  }
  const int n0 = nt * 128;
  const int m0 = blockIdx.y * 128;
  const int t = threadIdx.x, w = t >> 6, lane = t & 63;
  const int wm = w >> 1, wn = w & 1;
  const int mcol = lane & 15, quad = lane >> 4;
  const int lrow = lane >> 2, lcol = (lane & 3) * 8;   // staging map (16B/lane)

  const unsigned short* Ag = Xb + (size_t)m0 * HID + kbase;
  const unsigned short* Bg = Wb + (size_t)n0 * HID + kbase;

  f32x4 acc[4][4];
  #pragma unroll
  for (int i = 0; i < 4; i++)
    #pragma unroll
    for (int j = 0; j < 4; j++) acc[i][j] = (f32x4){0.f, 0.f, 0.f, 0.f};

  #define STAGE_QKV(buf, k0)                                                  \
    { const int c0 = w * 2, c1 = w * 2 + 1;                                   \
      gload_lds16(Ag + (size_t)(c0*16 + lrow) * HID + (k0) + lcol, &As[buf][c0 * 512]); \
      gload_lds16(Bg + (size_t)(c0*16 + lrow) * HID + (k0) + lcol, &Bs[buf][c0 * 512]); \
      gload_lds16(Ag + (size_t)(c1*16 + lrow) * HID + (k0) + lcol, &As[buf][c1 * 512]); \
      gload_lds16(Bg + (size_t)(c1*16 + lrow) * HID + (k0) + lcol, &Bs[buf][c1 * 512]); }

  STAGE_QKV(0, 0)
  STAGE_QKV(1, 32)
  asm volatile("s_waitcnt vmcnt(4)" ::: "memory");
  __builtin_amdgcn_s_barrier();
  __builtin_amdgcn_sched_barrier(0);

  int cur = 0, stg = 2;
  for (int kt = 0; kt < ntiles; ++kt) {
    if (kt + 2 < ntiles) STAGE_QKV(stg, (kt + 2) * 32)
    short8 af[4], bf[4];
    #pragma unroll
    for (int i = 0; i < 4; i++) af[i] = *(const short8*)&As[cur][(wm*64 + i*16 + mcol)*32 + quad*8];
    #pragma unroll
    for (int j = 0; j < 4; j++) bf[j] = *(const short8*)&Bs[cur][(wn*64 + j*16 + mcol)*32 + quad*8];
    #pragma unroll
    for (int i = 0; i < 4; i++)
      #pragma unroll
      for (int j = 0; j < 4; j++)
        acc[i][j] = __builtin_amdgcn_mfma_f32_16x16x32_bf16(af[i], bf[j], acc[i][j], 0, 0, 0);
    if (kt + 2 < ntiles) { asm volatile("s_waitcnt vmcnt(4)" ::: "memory"); }
    else                 { asm volatile("s_waitcnt vmcnt(0)" ::: "memory"); }
    __builtin_amdgcn_s_barrier();
    __builtin_amdgcn_sched_barrier(0);
    cur = (cur == 2) ? 0 : cur + 1;
    stg = (stg == 2) ? 0 : stg + 1;
  }

  if (isV) {
    unsigned short* dst = Vt + (size_t)(nt - 40) * HEAD_STRIDE;
    #pragma unroll
    for (int i = 0; i < 4; i++) {
      const int rb = m0 + wm*64 + i*16 + quad*4;   // 4 consecutive s per lane
      #pragma unroll
      for (int j = 0; j < 4; j++) {
        const int d = wn*64 + j*16 + mcol;
        ushort4 v4;
        v4.x = f2bf(acc[i][j][0]); v4.y = f2bf(acc[i][j][1]);
        v4.z = f2bf(acc[i][j][2]); v4.w = f2bf(acc[i][j][3]);
        *(ushort4*)(dst + (size_t)d * S_LEN + rb) = v4;
      }
    }
  } else {
    // Q|K: f32 partials into P32 [1024][5120]
    #pragma unroll
    for (int i = 0; i < 4; i++) {
      const int rb = m0 + wm*64 + i*16 + quad*4;   // C/D: row=(lane>>4)*4+reg
      #pragma unroll
      for (int j = 0; j < 4; j++) {
        const int nc = n0 + wn*64 + j*16 + mcol;   // col=lane&15
        #pragma unroll
        for (int r = 0; r < 4; r++)
          atomicAdd(p32ptr(P32a, P32b, (size_t)(rb + r) * 5120 + nc), acc[i][j][r]);
      }
    }
  }
}

// ---------------------------------------------------------------------------
// Kernel 2: RoPE finisher — reads f32 Q|K partials from P32, applies RoPE,
// writes bf16 Qraw [40][S][HD]. One wave per (head, s). Better precision
// than before (no pre-rope bf16 quantization).
// ---------------------------------------------------------------------------
__global__ __launch_bounds__(256) void rope_qk_k(
    const int* __restrict__ pos_ids,
    const float* __restrict__ P32a, const float* __restrict__ P32b,
    unsigned short* __restrict__ Qraw)
{
  const int w = threadIdx.x >> 6, lane = threadIdx.x & 63;
  const int gw = blockIdx.x * 4 + w;           // 0 .. 40*S-1
  const int hidx = gw >> 10;
  const int s = gw & 1023;
  const float pos = (float)pos_ids[s];
  const float invf = exp2f((float)lane * -0.20762050593045f);  // -log2(1e4)/64
  float sn, cs;
  sincosf(pos * invf, &sn, &cs);
  const size_t e0 = (size_t)s * 5120 + (size_t)hidx * 128 + lane;
  const float x0 = *p32ptr((float*)P32a, (float*)P32b, e0);
  const float x1 = *p32ptr((float*)P32a, (float*)P32b, e0 + 64);
  unsigned short* base = Qraw + (size_t)hidx * HEAD_STRIDE + (size_t)s * HD;
  base[lane]      = f2bf(x0 * cs - x1 * sn);
  base[lane + 64] = f2bf(x1 * cs + x0 * sn);
}

// ---------------------------------------------------------------------------
// Kernel 3: fused sparse attention (blocks 0..2047) + Wo fp32->bf16 convert
// (blocks 2048..6143) — unchanged from r12 (verified: cvt rides free).
// ---------------------------------------------------------------------------
#define SROW 1042           // f32 elements per score row
#define PSTR 2084           // ushort overlay stride (= 2*SROW)

// per-row residual refinement + fused exp/write sweep (register source)
#define PROC_ROW(UARR, RR, LL, PRE, PM, KRM, TTT)                             \
  {                                                                           \
    const int r_ = (RR);                                                      \
    const int L_ = (LL);                                                      \
    unsigned btau = (PRE);                                                    \
    unsigned bmsk = (PM);                                                     \
    int kr = (KRM);                                                           \
    int tt = (TTT);                                                           \
    const int bs = (bmsk == 0u) ? 31 : (__builtin_ctz(bmsk) - 1);             \
    _Pragma("unroll 1")                                                       \
    for (int b = bs; b >= 0; --b) {                                           \
      if (tt <= kr) break;                                                    \
      const unsigned bit = 1u << b;                                           \
      const unsigned am = bmsk | bit;                                         \
      const unsigned test = btau | bit;                                       \
      int cnt = 0;                                                            \
      _Pragma("unroll")                                                       \
      for (int c = 0; c < NC; c++) {                                          \
        const int j = c * 64 + lane;                                          \
        cnt += (int)__popcll(__ballot(j < L_ && ((UARR)[c] & am) == test));   \
      }                                                                       \
      if (cnt >= kr) { btau = test; tt = cnt; }                               \
      else           { kr -= cnt; tt -= cnt; }                                \
      bmsk = am;                                                              \
    }                                                                         \
    unsigned um = 0;                                                          \
    _Pragma("unroll")                                                         \
    for (int c = 0; c < NC; c++) {                                            \
      const int j = c * 64 + lane;                                            \
      if (j < L_ && (UARR)[c] > um) um = (UARR)[c];                           \
    }                                                                         \
    const float mx = iordf(wave_max_u(um));                                   \
    float ssum = 0.f;                                                         \
    if (tt <= kr) {                                                           \
      /* no tie-ranking needed: kept set == {u >= btau} (prefix order) */     \
      _Pragma("unroll")                                                       \
      for (int c = 0; c < NC; c++) {                                          \
        const int j = c * 64 + lane;                                          \
        const unsigned u = (UARR)[c];                                         \
        const bool kept = (j < L_) && ((u >= btau) || (j < MIN_IDX));         \
        const float e = kept ? __expf(iordf(u) - mx) : 0.f;                   \
        Pl[r_][c*64 + lane] = f2bf(e);                                        \
        ssum += e;                                                            \
      }                                                                       \
    } else {                                                                  \
      int tiebase = 0;                                                        \
      _Pragma("unroll")                                                       \
      for (int c = 0; c < NC; c++) {                                          \
        const int j = c * 64 + lane;                                          \
        const unsigned u = (UARR)[c];                                         \
        const unsigned umv = u & bmsk;                                        \
        const bool eq = (j < L_) && (umv == btau);                            \
        const unsigned long long bal = __ballot(eq);                          \
        const int trank = tiebase + (int)__popcll(bal & lmlt);                \
        tiebase += (int)__popcll(bal);                                        \
        const bool kept = (j < L_) &&                                         \
            ((umv > btau) || (eq && trank < kr) || (j < MIN_IDX));            \
        const float e = kept ? __expf(iordf(u) - mx) : 0.f;                   \
        Pl[r_][c*64 + lane] = f2bf(e);                                        \
        ssum += e;                                                            \
      }                                                                       \
    }                                                                         \
    ssum = wave_sum_f(ssum);                                                  \
    if (lane == 0) rowinv[r_] = 1.f / fmaxf(ssum, 1e-30f);                    \
  }

template<int KT>
__device__ __forceinline__ void attn_body(
    const unsigned short* __restrict__ Qb, const unsigned short* __restrict__ Kh,
    const unsigned short* __restrict__ Vh, unsigned short* __restrict__ AO,
    float (*S)[SROW], unsigned (*hist)[256], float* rowinv,
    int q0, int h, int w, int lane, int mcol, int quad)
{
  constexpr int NC = 2 * KT;                   // 64-key chunks per row
  const float scale = 0.08838834764831845f;    // 1/sqrt(128)
  unsigned short (*Pl)[PSTR] = (unsigned short (*)[PSTR])&S[0][0];
  const int wk = w & 3, wp = w >> 2;           // col-group / kt-parity

  short8 aq[4];
  {
    const unsigned short* qrow = Qb + ((size_t)h * S_LEN + q0 + mcol) * HD + quad * 8;
    #pragma unroll
    for (int kk = 0; kk < 4; kk++) aq[kk] = *(const short8*)(qrow + kk * 32);
  }

  // ---- Phase 1: scores straight into S; waves split by kt parity ----
  #pragma unroll
  for (int kt = wp; kt < KT; kt += 2) {
    short8 bfr[2][4];
    #pragma unroll
    for (int g2 = 0; g2 < 2; g2++) {
      const int key = kt * 128 + (wk * 2 + g2) * 16 + mcol;
      const unsigned short* krow = Kh + (size_t)key * HD + quad * 8;
      #pragma unroll
      for (int kk = 0; kk < 4; kk++) bfr[g2][kk] = *(const short8*)(krow + kk * 32);
    }
    f32x4 d4[2];
    d4[0] = (f32x4){0.f,0.f,0.f,0.f}; d4[1] = (f32x4){0.f,0.f,0.f,0.f};
    #pragma unroll
    for (int g2 = 0; g2 < 2; g2++)
      #pragma unroll
      for (int kk = 0; kk < 4; kk++)
        d4[g2] = __builtin_amdgcn_mfma_f32_16x16x32_bf16(aq[kk], bfr[g2][kk], d4[g2], 0, 0, 0);
    #pragma unroll
    for (int g2 = 0; g2 < 2; g2++) {
      const int ckey = kt * 128 + (wk * 2 + g2) * 16 + mcol;
      #pragma unroll
      for (int r = 0; r < 4; r++) S[quad*4 + r][ckey] = d4[g2][r] * scale;
    }
  }
  __syncthreads();                             // all scores visible

  // ---- Phase 2: one row pair per wave ----
  const unsigned long long lmlt = (1ull << lane) - 1ull;
  const int rep = lane & 3;
  {
    const int ra = w * 2, rbn = ra + 1;
    const int L0 = q0 + ra + 1, L1 = q0 + rbn + 1;
    unsigned u0[NC], u1[NC];
    #pragma unroll
    for (int c = 0; c < NC; c++) {
      u0[c] = ordf(S[ra][c*64 + lane]);
      u1[c] = ordf(S[rbn][c*64 + lane]);
    }
    int ks0 = L0 >> 1; if (ks0 < 1) ks0 = 1;
    int ks1 = L1 >> 1; if (ks1 < 1) ks1 = 1;
    int krem0 = ks0, tot0 = L0, krem1 = ks1, tot1 = L1;
    unsigned pre0 = 0u, pre1 = 0u, pm0 = 0u, pm1 = 0u;

    #pragma unroll
    for (int pass = 0; pass < 3; pass++) {
      const int shift = 26 - pass * 6;
      const bool a0 = tot0 > krem0, a1 = tot1 > krem1;
      if (!a0 && !a1) continue;                // wave-uniform
      { uint4 z = {0u, 0u, 0u, 0u}; *(uint4*)&hist[w][lane * 4] = z; }
      wave_lds_fence();
      #pragma unroll
      for (int c = 0; c < NC; c++) {
        const int j = c * 64 + lane;
        if (a0 && j < L0 && (u0[c] & pm0) == pre0)
          atomicAdd(&hist[w][((u0[c] >> shift) & 63) * 4 + rep], 1u);
        if (a1 && j < L1 && (u1[c] & pm1) == pre1)
          atomicAdd(&hist[w][((u1[c] >> shift) & 63) * 4 + rep], 1u << 16);
      }
      wave_lds_fence();
      // merge replicas + packed descending scan (1 bin/lane, bin = 63-lane)
      const uint4 cv = *(const uint4*)&hist[w][(63 - lane) * 4];
      const unsigned cnt2 = cv.x + cv.y + cv.z + cv.w;  // 2 rows packed 16b
      unsigned x = cnt2;
      #pragma unroll
      for (int d2 = 1; d2 < 64; d2 <<= 1) { unsigned y = __shfl_up(x, d2); if (lane >= d2) x += y; }
      const unsigned runp = x - cnt2;            // count in bins above mine
      if (a0) {
        const int run = (int)(runp & 0xFFFFu);
        const int cn  = (int)(cnt2 & 0xFFFFu);
        const bool hit = (run < krem0) && (run + cn >= krem0);
        unsigned packv = hit ? (((unsigned)(63 - lane) << 22) |
                                ((unsigned)run << 11) | (unsigned)cn) : 0u;
        const unsigned long long bal = __ballot(hit);
        const int srcl = __ffsll(bal) - 1;
        const unsigned res = __shfl(packv, srcl);
        krem0 -= (int)((res >> 11) & 0x7FF);
        tot0 = (int)(res & 0x7FF);
        pre0 |= ((unsigned)(res >> 22)) << shift;
        pm0 |= 63u << shift;
      }
      if (a1) {
        const int run = (int)(runp >> 16);
        const int cn  = (int)(cnt2 >> 16);
        const bool hit = (run < krem1) && (run + cn >= krem1);
        unsigned packv = hit ? (((unsigned)(63 - lane) << 22) |
                                ((unsigned)run << 11) | (unsigned)cn) : 0u;
        const unsigned long long bal = __ballot(hit);
        const int srcl = __ffsll(bal) - 1;
        const unsigned res = __shfl(packv, srcl);
        krem1 -= (int)((res >> 11) & 0x7FF);
        tot1 = (int)(res & 0x7FF);
        pre1 |= ((unsigned)(res >> 22)) << shift;
        pm1 |= 63u << shift;
      }
    }
    PROC_ROW(u0, ra,  L0, pre0, pm0, krem0, tot0)
    PROC_ROW(u1, rbn, L1, pre1, pm1, krem1, tot1)
  }
  __syncthreads();

  // ---- Phase 3: PV; each wave owns one 16-wide d-group ----
  f32x4 opv = (f32x4){0.f,0.f,0.f,0.f};
  const int d = w * 16 + mcol;
  #pragma unroll
  for (int kt = 0; kt < KT; kt++) {
    #pragma unroll
    for (int kb = 0; kb < 4; kb++) {
      short8 af = *(const short8*)&Pl[mcol][kt*128 + kb*32 + quad*8];
      short8 bfr = *(const short8*)(Vh + (size_t)d * S_LEN + kt*128 + kb*32 + quad*8);
      opv = __builtin_amdgcn_mfma_f32_16x16x32_bf16(af, bfr, opv, 0, 0, 0);
    }
  }
  {
    const int col = h * HD + d;
    #pragma unroll
    for (int r2 = 0; r2 < 4; r2++) {
      const int row = q0 + quad*4 + r2;
      AO[(size_t)row * AO_COLS + col] = f2bf(opv[r2] * rowinv[quad*4 + r2]);
    }
  }
}

__global__ __launch_bounds__(512, 4) void attn_k(
    const unsigned short* __restrict__ Qb, const unsigned short* __restrict__ Kb,
    const unsigned short* __restrict__ Vt, unsigned short* __restrict__ AO,
    const float* __restrict__ WoF, unsigned short* __restrict__ Wob)
{
  __shared__ float S[16][SROW];                // 66,688 B (P bf16 overlays)
  __shared__ unsigned hist[8][256];            // 8192 B (64 bins x 4 replicas)
  __shared__ float rowinv[16];
  const int bid = (int)blockIdx.x;
  if (bid >= 2048) {
    // Wo convert: 512 threads x 8 elems = 4096 per block; blocks 2048..6143
    const size_t i = ((size_t)(bid - 2048) * 512 + threadIdx.x) * 8;
    float4 a = *(const float4*)(WoF + i);
    float4 c = *(const float4*)(WoF + i + 4);
    *(short8*)(Wob + i) = pack8(a, c);
    return;
  }
  const int bx = bid & 63;
  const int h = bid >> 6;
  const int rb = 63 - bx;                      // heavy blocks first
  const int kvh = h >> 2;                      // GROUPS=4
  const int q0 = rb * 16;
  const int kt_max = (rb >> 3) + 1;            // == (q0+16+127)>>7
  const int t = threadIdx.x, w = t >> 6, lane = t & 63;
  const int mcol = lane & 15, quad = lane >> 4;
  const unsigned short* Kh = Kb + (size_t)kvh * HEAD_STRIDE;  // [s][d]
  const unsigned short* Vh = Vt + (size_t)kvh * HEAD_STRIDE;  // [d][s]

  switch (kt_max) {
    case 1: attn_body<1>(Qb, Kh, Vh, AO, S, hist, rowinv, q0, h, w, lane, mcol, quad); break;
    case 2: attn_body<2>(Qb, Kh, Vh, AO, S, hist, rowinv, q0, h, w, lane, mcol, quad); break;
    case 3: attn_body<3>(Qb, Kh, Vh, AO, S, hist, rowinv, q0, h, w, lane, mcol, quad); break;
    case 4: attn_body<4>(Qb, Kh, Vh, AO, S, hist, rowinv, q0, h, w, lane, mcol, quad); break;
    case 5: attn_body<5>(Qb, Kh, Vh, AO, S, hist, rowinv, q0, h, w, lane, mcol, quad); break;
    case 6: attn_body<6>(Qb, Kh, Vh, AO, S, hist, rowinv, q0, h, w, lane, mcol, quad); break;
    case 7: attn_body<7>(Qb, Kh, Vh, AO, S, hist, rowinv, q0, h, w, lane, mcol, quad); break;
    default: attn_body<8>(Qb, Kh, Vh, AO, S, hist, rowinv, q0, h, w, lane, mcol, quad); break;
  }
}

// ---------------------------------------------------------------------------
// Kernel 4: output projection, 128x128 tiles, SPLIT-K=2 (grid (32,8,2) = 512
// blocks = 2/CU). Each z computes K half and atomicAdd's f32 partials into
// the pre-zeroed Out (unchanged from r12).
// ---------------------------------------------------------------------------
__global__ __launch_bounds__(256) void gemm_out_k(
    const unsigned short* __restrict__ A, const unsigned short* __restrict__ Wob,
    float* __restrict__ Out)
{
  __shared__ unsigned short As[3][128 * 32];
  __shared__ unsigned short Bs[3][128 * 32];
  const int n0 = blockIdx.x * 128;
  const int m0 = blockIdx.y * 128;
  const int kbase = blockIdx.z * 2048;
  const int t = threadIdx.x, w = t >> 6, lane = t & 63;
  const int wm = w >> 1, wn = w & 1;
  const int mcol = lane & 15, quad = lane >> 4;
  const int lrow = lane >> 2, lcol = (lane & 3) * 8;

  const unsigned short* Ag = A   + (size_t)m0 * AO_COLS + kbase;
  const unsigned short* Bg = Wob + (size_t)n0 * AO_COLS + kbase;

  f32x4 acc[4][4];
  #pragma unroll
  for (int i = 0; i < 4; i++)
    #pragma unroll
    for (int j = 0; j < 4; j++) acc[i][j] = (f32x4){0.f, 0.f, 0.f, 0.f};

  constexpr int NT = 2048 / 32;            // 64 K-tiles per split
  #define STAGE_OUT(buf, k0)                                                  \
    { const int c0 = w * 2, c1 = w * 2 + 1;                                   \
      gload_lds16(Ag + (size_t)(c0*16 + lrow) * AO_COLS + (k0) + lcol, &As[buf][c0 * 512]); \
      gload_lds16(Bg + (size_t)(c0*16 + lrow) * AO_COLS + (k0) + lcol, &Bs[buf][c0 * 512]); \
      gload_lds16(Ag + (size_t)(c1*16 + lrow) * AO_COLS + (k0) + lcol, &As[buf][c1 * 512]); \
      gload_lds16(Bg + (size_t)(c1*16 + lrow) * AO_COLS + (k0) + lcol, &Bs[buf][c1 * 512]); }

  STAGE_OUT(0, 0)
  STAGE_OUT(1, 32)
  asm volatile("s_waitcnt vmcnt(4)" ::: "memory");
  __builtin_amdgcn_s_barrier();
  __builtin_amdgcn_sched_barrier(0);

  int cur = 0, stg = 2;
  for (int kt = 0; kt < NT; ++kt) {
    if (kt + 2 < NT) STAGE_OUT(stg, (kt + 2) * 32)
    short8 af[4], bf[4];
    #pragma unroll
    for (int i = 0; i < 4; i++) af[i] = *(const short8*)&As[cur][(wm*64 + i*16 + mcol)*32 + quad*8];
    #pragma unroll
    for (int j = 0; j < 4; j++) bf[j] = *(const short8*)&Bs[cur][(wn*64 + j*16 + mcol)*32 + quad*8];
    #pragma unroll
    for (int i = 0; i < 4; i++)
      #pragma unroll
      for (int j = 0; j < 4; j++)
        acc[i][j] = __builtin_amdgcn_mfma_f32_16x16x32_bf16(af[i], bf[j], acc[i][j], 0, 0, 0);
    if (kt + 2 < NT) { asm volatile("s_waitcnt vmcnt(4)" ::: "memory"); }
    else             { asm volatile("s_waitcnt vmcnt(0)" ::: "memory"); }
    __builtin_amdgcn_s_barrier();
    __builtin_amdgcn_sched_barrier(0);
    cur = (cur == 2) ? 0 : cur + 1;
    stg = (stg == 2) ? 0 : stg + 1;
  }

  #pragma unroll
  for (int i = 0; i < 4; i++) {
    const int rb = m0 + wm*64 + i*16 + quad*4;
    #pragma unroll
    for (int j = 0; j < 4; j++) {
      const int col = n0 + wn*64 + j*16 + mcol;
      #pragma unroll
      for (int r = 0; r < 4; r++)
        atomicAdd(&Out[(size_t)(rb + r) * HID + col], acc[i][j][r]);
    }
  }
}

// ---------------------------------------------------------------------------
// Workspace layout (79,691,776 bytes total):
//   [0)          Qraw  bf16 [40][S][HD] (Q|K contiguous)   10,485,760
//   [+10485760)  Vt    bf16 [NKV][HD][S]                    2,097,152
//   [+12582912)  AO    bf16 [S][NH*HD]                      8,388,608
//                 (first 4MB doubles as P32 tail during QKV gemm)
//   [+20971520)  Xb    bf16 [S][HID]                        8,388,608
//   [+29360128)  Wqkvb bf16 [6144][4096]                   50,331,648
//                Wob   bf16 [4096][4096] aliases Wqkvb (cvt during attn)
//   P32 f32 [1024][5120] = out (16,777,216 B) ++ AO[0:4,194,304 B)
// ---------------------------------------------------------------------------
extern "C" void kernel_launch(void* const* d_in, const int* in_sizes, int n_in,
                              void* d_out, int out_size, void* d_ws, size_t ws_size,
                              hipStream_t stream) {
  (void)in_sizes; (void)n_in; (void)out_size; (void)ws_size;
  const float* X   = (const float*)d_in[0];
  const int*   pos = (const int*)d_in[1];
  const float* Wq  = (const float*)d_in[2];
  const float* Wk  = (const float*)d_in[3];
  const float* Wv  = (const float*)d_in[4];
  const float* Wo  = (const float*)d_in[5];
  float* out = (float*)d_out;

  char* ws = (char*)d_ws;
  unsigned short* Qraw  = (unsigned short*)ws;
  unsigned short* Kraw  = (unsigned short*)(ws + 8388608);    // = Qraw + 32 heads
  unsigned short* Vt    = (unsigned short*)(ws + 10485760);
  unsigned short* AO    = (unsigned short*)(ws + 12582912);
  float*          AOf   = (float*)AO;                         // P32 tail (4MB)
  unsigned short* Xb    = (unsigned short*)(ws + 20971520);
  unsigned short* Wqkvb = (unsigned short*)(ws + 29360128);
  unsigned short* Wob   = Wqkvb;   // alias: Wo converted during attn launch

  // bf16 conversions: X, Wq, Wk, Wv fused into one launch
  cvt4_k<<<dim3(14336), dim3(256), 0, stream>>>(X, Wq, Wk, Wv, Xb, Wqkvb);

  // zero P32 (= out ++ first 4MB of AO) for split-K atomics
  hipMemsetAsync(out, 0, (size_t)P32_SPLIT * sizeof(float), stream);
  hipMemsetAsync(AOf, 0, 4194304, stream);

  gemm_qkv_k<<<dim3(88, 8),  dim3(256), 0, stream>>>(Xb, Wqkvb, out, AOf, Vt);
  rope_qk_k <<<dim3(10240),  dim3(256), 0, stream>>>(pos, out, AOf, Qraw);

  // re-zero out for gemm_out's split-K atomics (P32a consumed by rope)
  hipMemsetAsync(out, 0, (size_t)S_LEN * HID * sizeof(float), stream);

  // fused: attention (blocks 0..2047) + Wo convert (blocks 2048..6143)
  attn_k    <<<dim3(6144),   dim3(512), 0, stream>>>(Qraw, Kraw, Vt, AO, Wo, Wob);
  gemm_out_k<<<dim3(32, 8, 2), dim3(256), 0, stream>>>(AO, Wob, out);
}

// Round 19
// 441.977 us; speedup vs baseline: 1.1215x; 1.1215x over previous
//
#include <hip/hip_runtime.h>
#include <hip/hip_bf16.h>

// Problem constants
#define S_LEN 1024
#define HID   4096
#define NH    32
#define NKV   8
#define HD    128
#define MIN_IDX 4
#define AO_COLS 4096        // NH*HD
#define HEAD_STRIDE 131072  // S_LEN*HD

typedef __attribute__((ext_vector_type(8))) short short8;
typedef __attribute__((ext_vector_type(4))) float f32x4;

__device__ __forceinline__ unsigned short f2bf(float f) {
  union { float f; unsigned u; } v; v.f = f;
  unsigned r = v.u + 0x7FFFu + ((v.u >> 16) & 1u);   // RNE
  return (unsigned short)(r >> 16);
}
__device__ __forceinline__ float bf2f(unsigned short h) {
  union { unsigned u; float f; } v; v.u = ((unsigned)h) << 16;
  return v.f;
}
__device__ __forceinline__ unsigned pk2(float a, float b) {
  union { __hip_bfloat162 h; unsigned u; } c;
  c.h = __float22bfloat162_rn(make_float2(a, b));    // v_cvt_pk_bf16_f32
  return c.u;
}
__device__ __forceinline__ short8 pack8(float4 a, float4 b) {
  union { short8 s; unsigned u[4]; } r;
  r.u[0] = pk2(a.x, a.y); r.u[1] = pk2(a.z, a.w);
  r.u[2] = pk2(b.x, b.y); r.u[3] = pk2(b.z, b.w);
  return r.s;
}
// float -> order-preserving uint, and inverse
__device__ __forceinline__ unsigned ordf(float f) {
  union { float f; int i; } v; v.f = f;
  return (unsigned)(v.i ^ ((v.i >> 31) | 0x80000000));
}
__device__ __forceinline__ float iordf(unsigned u) {
  union { int i; float f; } v;
  v.i = (u & 0x80000000u) ? (int)(u ^ 0x80000000u) : (int)~u;
  return v.f;
}
__device__ __forceinline__ float wave_sum_f(float v) {
  #pragma unroll
  for (int m = 32; m >= 1; m >>= 1) v += __shfl_xor(v, m);
  return v;
}
__device__ __forceinline__ unsigned wave_max_u(unsigned v) {
  #pragma unroll
  for (int m = 32; m >= 1; m >>= 1) { unsigned o = __shfl_xor(v, m); v = o > v ? o : v; }
  return v;
}
// wave-local LDS fence: hist[w] is wave-private, so no block barrier needed.
// Wait lgkmcnt(0) only (vmcnt=63, expcnt=7 -> don't wait): imm = 0xC07F.
__device__ __forceinline__ void wave_lds_fence() {
  __builtin_amdgcn_s_waitcnt(0xC07F);
  __builtin_amdgcn_wave_barrier();      // stop compiler reordering
}
// async global->LDS, 16 B per lane. LDS dest: wave-uniform base + lane*16.
__device__ __forceinline__ void gload_lds16(const unsigned short* g, unsigned short* l) {
  auto gp = (const __attribute__((address_space(1))) unsigned*)g;
  auto lp = (__attribute__((address_space(3))) unsigned*)(unsigned)(unsigned long long)l;
  __builtin_amdgcn_global_load_lds(gp, lp, 16, 0, 0);
}

// ---------------------------------------------------------------------------
// Kernel 0: fused convert of X, Wq, Wk, Wv (14336 blocks, 2048 elem/blk).
// ---------------------------------------------------------------------------
__global__ __launch_bounds__(256) void cvt4_k(
    const float* __restrict__ s0, const float* __restrict__ s1,
    const float* __restrict__ s2, const float* __restrict__ s3,
    unsigned short* __restrict__ d0, unsigned short* __restrict__ d1)
{
  const int b = blockIdx.x;
  const float* src; unsigned short* dst; int rb;
  if (b < 2048)       { src = s0; dst = d0;            rb = b; }
  else if (b < 10240) { src = s1; dst = d1;            rb = b - 2048; }
  else if (b < 12288) { src = s2; dst = d1 + 16777216; rb = b - 10240; }
  else                { src = s3; dst = d1 + 20971520; rb = b - 12288; }
  const size_t i = ((size_t)rb * 256 + threadIdx.x) * 8;
  float4 a = *(const float4*)(src + i);
  float4 c = *(const float4*)(src + i + 4);
  *(short8*)(dst + i) = pack8(a, c);
}

// ---------------------------------------------------------------------------
// Kernel 1: QKV projection, 128x128 tiles (r8-proven), grid (48,8).
// Depth-2 pipeline: 3-buffer LDS, counted s_waitcnt vmcnt(4), 1 barrier/iter.
// N-tiles 0..39 -> Q|K heads ([40][S][HD] contiguous at Qraw); 40..47 -> Vt.
// ---------------------------------------------------------------------------
__global__ __launch_bounds__(256) void gemm_qkv_k(
    const unsigned short* __restrict__ Xb, const unsigned short* __restrict__ Wb,
    unsigned short* __restrict__ Qraw, unsigned short* __restrict__ Vt)
{
  __shared__ unsigned short As[3][128 * 32];
  __shared__ unsigned short Bs[3][128 * 32];
  const int nt = blockIdx.x;               // 0..47
  const int n0 = nt * 128;
  const int m0 = blockIdx.y * 128;
  const int t = threadIdx.x, w = t >> 6, lane = t & 63;
  const int wm = w >> 1, wn = w & 1;
  const int mcol = lane & 15, quad = lane >> 4;
  const int lrow = lane >> 2, lcol = (lane & 3) * 8;   // staging map (16B/lane)

  const unsigned short* Ag = Xb + (size_t)m0 * HID;
  const unsigned short* Bg = Wb + (size_t)n0 * HID;

  f32x4 acc[4][4];
  #pragma unroll
  for (int i = 0; i < 4; i++)
    #pragma unroll
    for (int j = 0; j < 4; j++) acc[i][j] = (f32x4){0.f, 0.f, 0.f, 0.f};

  constexpr int NT = HID / 32;             // 128 K-tiles
  #define STAGE_QKV(buf, k0)                                                  \
    { const int c0 = w * 2, c1 = w * 2 + 1;                                   \
      gload_lds16(Ag + (size_t)(c0*16 + lrow) * HID + (k0) + lcol, &As[buf][c0 * 512]); \
      gload_lds16(Bg + (size_t)(c0*16 + lrow) * HID + (k0) + lcol, &Bs[buf][c0 * 512]); \
      gload_lds16(Ag + (size_t)(c1*16 + lrow) * HID + (k0) + lcol, &As[buf][c1 * 512]); \
      gload_lds16(Bg + (size_t)(c1*16 + lrow) * HID + (k0) + lcol, &Bs[buf][c1 * 512]); }

  STAGE_QKV(0, 0)
  STAGE_QKV(1, 32)
  asm volatile("s_waitcnt vmcnt(4)" ::: "memory");
  __builtin_amdgcn_s_barrier();
  __builtin_amdgcn_sched_barrier(0);

  int cur = 0, stg = 2;
  for (int kt = 0; kt < NT; ++kt) {
    if (kt + 2 < NT) STAGE_QKV(stg, (kt + 2) * 32)
    short8 af[4], bf[4];
    #pragma unroll
    for (int i = 0; i < 4; i++) af[i] = *(const short8*)&As[cur][(wm*64 + i*16 + mcol)*32 + quad*8];
    #pragma unroll
    for (int j = 0; j < 4; j++) bf[j] = *(const short8*)&Bs[cur][(wn*64 + j*16 + mcol)*32 + quad*8];
    #pragma unroll
    for (int i = 0; i < 4; i++)
      #pragma unroll
      for (int j = 0; j < 4; j++)
        acc[i][j] = __builtin_amdgcn_mfma_f32_16x16x32_bf16(af[i], bf[j], acc[i][j], 0, 0, 0);
    if (kt + 2 < NT) { asm volatile("s_waitcnt vmcnt(4)" ::: "memory"); }
    else             { asm volatile("s_waitcnt vmcnt(0)" ::: "memory"); }
    __builtin_amdgcn_s_barrier();
    __builtin_amdgcn_sched_barrier(0);
    cur = (cur == 2) ? 0 : cur + 1;
    stg = (stg == 2) ? 0 : stg + 1;
  }

  if (nt < 40) {
    unsigned short* dst = Qraw + (size_t)nt * HEAD_STRIDE;   // Q|K contiguous
    #pragma unroll
    for (int i = 0; i < 4; i++) {
      const int rb = m0 + wm*64 + i*16 + quad*4;   // C/D: row=(lane>>4)*4+reg
      #pragma unroll
      for (int j = 0; j < 4; j++) {
        const int d = wn*64 + j*16 + mcol;         // col=lane&15
        #pragma unroll
        for (int r = 0; r < 4; r++)
          dst[(size_t)(rb + r) * HD + d] = f2bf(acc[i][j][r]);
      }
    }
  } else {
    unsigned short* dst = Vt + (size_t)(nt - 40) * HEAD_STRIDE;
    #pragma unroll
    for (int i = 0; i < 4; i++) {
      const int rb = m0 + wm*64 + i*16 + quad*4;   // 4 consecutive s per lane
      #pragma unroll
      for (int j = 0; j < 4; j++) {
        const int d = wn*64 + j*16 + mcol;
        ushort4 v4;
        v4.x = f2bf(acc[i][j][0]); v4.y = f2bf(acc[i][j][1]);
        v4.z = f2bf(acc[i][j][2]); v4.w = f2bf(acc[i][j][3]);
        *(ushort4*)(dst + (size_t)d * S_LEN + rb) = v4;
      }
    }
  }
}

// ---------------------------------------------------------------------------
// Kernel 2: RoPE in-place on bf16 Q|K (contiguous [40][S][HD]).
// ---------------------------------------------------------------------------
__global__ __launch_bounds__(256) void rope_qk_k(
    const int* __restrict__ pos_ids, unsigned short* __restrict__ Qraw)
{
  const int w = threadIdx.x >> 6, lane = threadIdx.x & 63;
  const int gw = blockIdx.x * 4 + w;           // 0 .. (NH+NKV)*S-1
  const int hidx = gw >> 10;
  const int s = gw & 1023;
  const float pos = (float)pos_ids[s];
  const float invf = exp2f((float)lane * -0.20762050593045f);  // -log2(1e4)/64
  float sn, cs;
  sincosf(pos * invf, &sn, &cs);
  unsigned short* base = Qraw + (size_t)hidx * HEAD_STRIDE + (size_t)s * HD;
  const float x0 = bf2f(base[lane]), x1 = bf2f(base[lane + 64]);
  base[lane]      = f2bf(x0 * cs - x1 * sn);
  base[lane + 64] = f2bf(x1 * cs + x0 * sn);
}

// ---------------------------------------------------------------------------
// Kernel 3: fused sparse attention (blocks 0..2047) + Wo fp32->bf16 convert
// (blocks 2048..6143) in ONE launch: the memory-bound cvt runs in attn's
// idle HBM bandwidth / tail. Wob aliases Wqkvb (dead after gemm_qkv).
// attn: 512 threads (8 waves), spill-free full-width-S, per-wave row pair,
// replicated 64-bin histogram select + fast sweep (r9-proven).
// ---------------------------------------------------------------------------
#define SROW 1042           // f32 elements per score row
#define PSTR 2084           // ushort overlay stride (= 2*SROW)

// per-row residual refinement + fused exp/write sweep (register source)
#define PROC_ROW(UARR, RR, LL, PRE, PM, KRM, TTT)                             \
  {                                                                           \
    const int r_ = (RR);                                                      \
    const int L_ = (LL);                                                      \
    unsigned btau = (PRE);                                                    \
    unsigned bmsk = (PM);                                                     \
    int kr = (KRM);                                                           \
    int tt = (TTT);                                                           \
    const int bs = (bmsk == 0u) ? 31 : (__builtin_ctz(bmsk) - 1);             \
    _Pragma("unroll 1")                                                       \
    for (int b = bs; b >= 0; --b) {                                           \
      if (tt <= kr) break;                                                    \
      const unsigned bit = 1u << b;                                           \
      const unsigned am = bmsk | bit;                                         \
      const unsigned test = btau | bit;                                       \
      int cnt = 0;                                                            \
      _Pragma("unroll")                                                       \
      for (int c = 0; c < NC; c++) {                                          \
        const int j = c * 64 + lane;                                          \
        cnt += (int)__popcll(__ballot(j < L_ && ((UARR)[c] & am) == test));   \
      }                                                                       \
      if (cnt >= kr) { btau = test; tt = cnt; }                               \
      else           { kr -= cnt; tt -= cnt; }                                \
      bmsk = am;                                                              \
    }                                                                         \
    unsigned um = 0;                                                          \
    _Pragma("unroll")                                                         \
    for (int c = 0; c < NC; c++) {                                            \
      const int j = c * 64 + lane;                                            \
      if (j < L_ && (UARR)[c] > um) um = (UARR)[c];                           \
    }                                                                         \
    const float mx = iordf(wave_max_u(um));                                   \
    float ssum = 0.f;                                                         \
    if (tt <= kr) {                                                           \
      /* no tie-ranking needed: kept set == {u >= btau} (prefix order) */     \
      _Pragma("unroll")                                                       \
      for (int c = 0; c < NC; c++) {                                          \
        const int j = c * 64 + lane;                                          \
        const unsigned u = (UARR)[c];                                         \
        const bool kept = (j < L_) && ((u >= btau) || (j < MIN_IDX));         \
        const float e = kept ? __expf(iordf(u) - mx) : 0.f;                   \
        Pl[r_][c*64 + lane] = f2bf(e);                                        \
        ssum += e;                                                            \
      }                                                                       \
    } else {                                                                  \
      int tiebase = 0;                                                        \
      _Pragma("unroll")                                                       \
      for (int c = 0; c < NC; c++) {                                          \
        const int j = c * 64 + lane;                                          \
        const unsigned u = (UARR)[c];                                         \
        const unsigned umv = u & bmsk;                                        \
        const bool eq = (j < L_) && (umv == btau);                            \
        const unsigned long long bal = __ballot(eq);                          \
        const int trank = tiebase + (int)__popcll(bal & lmlt);                \
        tiebase += (int)__popcll(bal);                                        \
        const bool kept = (j < L_) &&                                         \
            ((umv > btau) || (eq && trank < kr) || (j < MIN_IDX));            \
        const float e = kept ? __expf(iordf(u) - mx) : 0.f;                   \
        Pl[r_][c*64 + lane] = f2bf(e);                                        \
        ssum += e;                                                            \
      }                                                                       \
    }                                                                         \
    ssum = wave_sum_f(ssum);                                                  \
    if (lane == 0) rowinv[r_] = 1.f / fmaxf(ssum, 1e-30f);                    \
  }

template<int KT>
__device__ __forceinline__ void attn_body(
    const unsigned short* __restrict__ Qb, const unsigned short* __restrict__ Kh,
    const unsigned short* __restrict__ Vh, unsigned short* __restrict__ AO,
    float (*S)[SROW], unsigned (*hist)[256], float* rowinv,
    int q0, int h, int w, int lane, int mcol, int quad)
{
  constexpr int NC = 2 * KT;                   // 64-key chunks per row
  const float scale = 0.08838834764831845f;    // 1/sqrt(128)
  unsigned short (*Pl)[PSTR] = (unsigned short (*)[PSTR])&S[0][0];
  const int wk = w & 3, wp = w >> 2;           // col-group / kt-parity

  short8 aq[4];
  {
    const unsigned short* qrow = Qb + ((size_t)h * S_LEN + q0 + mcol) * HD + quad * 8;
    #pragma unroll
    for (int kk = 0; kk < 4; kk++) aq[kk] = *(const short8*)(qrow + kk * 32);
  }

  // ---- Phase 1: scores straight into S; waves split by kt parity ----
  #pragma unroll
  for (int kt = wp; kt < KT; kt += 2) {
    short8 bfr[2][4];
    #pragma unroll
    for (int g2 = 0; g2 < 2; g2++) {
      const int key = kt * 128 + (wk * 2 + g2) * 16 + mcol;
      const unsigned short* krow = Kh + (size_t)key * HD + quad * 8;
      #pragma unroll
      for (int kk = 0; kk < 4; kk++) bfr[g2][kk] = *(const short8*)(krow + kk * 32);
    }
    f32x4 d4[2];
    d4[0] = (f32x4){0.f,0.f,0.f,0.f}; d4[1] = (f32x4){0.f,0.f,0.f,0.f};
    #pragma unroll
    for (int g2 = 0; g2 < 2; g2++)
      #pragma unroll
      for (int kk = 0; kk < 4; kk++)
        d4[g2] = __builtin_amdgcn_mfma_f32_16x16x32_bf16(aq[kk], bfr[g2][kk], d4[g2], 0, 0, 0);
    #pragma unroll
    for (int g2 = 0; g2 < 2; g2++) {
      const int ckey = kt * 128 + (wk * 2 + g2) * 16 + mcol;
      #pragma unroll
      for (int r = 0; r < 4; r++) S[quad*4 + r][ckey] = d4[g2][r] * scale;
    }
  }
  __syncthreads();                             // all scores visible

  // ---- Phase 2: one row pair per wave ----
  const unsigned long long lmlt = (1ull << lane) - 1ull;
  const int rep = lane & 3;
  {
    const int ra = w * 2, rbn = ra + 1;
    const int L0 = q0 + ra + 1, L1 = q0 + rbn + 1;
    unsigned u0[NC], u1[NC];
    #pragma unroll
    for (int c = 0; c < NC; c++) {
      u0[c] = ordf(S[ra][c*64 + lane]);
      u1[c] = ordf(S[rbn][c*64 + lane]);
    }
    int ks0 = L0 >> 1; if (ks0 < 1) ks0 = 1;
    int ks1 = L1 >> 1; if (ks1 < 1) ks1 = 1;
    int krem0 = ks0, tot0 = L0, krem1 = ks1, tot1 = L1;
    unsigned pre0 = 0u, pre1 = 0u, pm0 = 0u, pm1 = 0u;

    #pragma unroll
    for (int pass = 0; pass < 3; pass++) {
      const int shift = 26 - pass * 6;
      const bool a0 = tot0 > krem0, a1 = tot1 > krem1;
      if (!a0 && !a1) continue;                // wave-uniform
      { uint4 z = {0u, 0u, 0u, 0u}; *(uint4*)&hist[w][lane * 4] = z; }
      wave_lds_fence();
      #pragma unroll
      for (int c = 0; c < NC; c++) {
        const int j = c * 64 + lane;
        if (a0 && j < L0 && (u0[c] & pm0) == pre0)
          atomicAdd(&hist[w][((u0[c] >> shift) & 63) * 4 + rep], 1u);
        if (a1 && j < L1 && (u1[c] & pm1) == pre1)
          atomicAdd(&hist[w][((u1[c] >> shift) & 63) * 4 + rep], 1u << 16);
      }
      wave_lds_fence();
      // merge replicas + packed descending scan (1 bin/lane, bin = 63-lane)
      const uint4 cv = *(const uint4*)&hist[w][(63 - lane) * 4];
      const unsigned cnt2 = cv.x + cv.y + cv.z + cv.w;  // 2 rows packed 16b
      unsigned x = cnt2;
      #pragma unroll
      for (int d2 = 1; d2 < 64; d2 <<= 1) { unsigned y = __shfl_up(x, d2); if (lane >= d2) x += y; }
      const unsigned runp = x - cnt2;            // count in bins above mine
      if (a0) {
        const int run = (int)(runp & 0xFFFFu);
        const int cn  = (int)(cnt2 & 0xFFFFu);
        const bool hit = (run < krem0) && (run + cn >= krem0);
        unsigned packv = hit ? (((unsigned)(63 - lane) << 22) |
                                ((unsigned)run << 11) | (unsigned)cn) : 0u;
        const unsigned long long bal = __ballot(hit);
        const int srcl = __ffsll(bal) - 1;
        const unsigned res = __shfl(packv, srcl);
        krem0 -= (int)((res >> 11) & 0x7FF);
        tot0 = (int)(res & 0x7FF);
        pre0 |= ((unsigned)(res >> 22)) << shift;
        pm0 |= 63u << shift;
      }
      if (a1) {
        const int run = (int)(runp >> 16);
        const int cn  = (int)(cnt2 >> 16);
        const bool hit = (run < krem1) && (run + cn >= krem1);
        unsigned packv = hit ? (((unsigned)(63 - lane) << 22) |
                                ((unsigned)run << 11) | (unsigned)cn) : 0u;
        const unsigned long long bal = __ballot(hit);
        const int srcl = __ffsll(bal) - 1;
        const unsigned res = __shfl(packv, srcl);
        krem1 -= (int)((res >> 11) & 0x7FF);
        tot1 = (int)(res & 0x7FF);
        pre1 |= ((unsigned)(res >> 22)) << shift;
        pm1 |= 63u << shift;
      }
    }
    PROC_ROW(u0, ra,  L0, pre0, pm0, krem0, tot0)
    PROC_ROW(u1, rbn, L1, pre1, pm1, krem1, tot1)
  }
  __syncthreads();

  // ---- Phase 3: PV; each wave owns one 16-wide d-group ----
  f32x4 opv = (f32x4){0.f,0.f,0.f,0.f};
  const int d = w * 16 + mcol;
  #pragma unroll
  for (int kt = 0; kt < KT; kt++) {
    #pragma unroll
    for (int kb = 0; kb < 4; kb++) {
      short8 af = *(const short8*)&Pl[mcol][kt*128 + kb*32 + quad*8];
      short8 bfr = *(const short8*)(Vh + (size_t)d * S_LEN + kt*128 + kb*32 + quad*8);
      opv = __builtin_amdgcn_mfma_f32_16x16x32_bf16(af, bfr, opv, 0, 0, 0);
    }
  }
  {
    const int col = h * HD + d;
    #pragma unroll
    for (int r2 = 0; r2 < 4; r2++) {
      const int row = q0 + quad*4 + r2;
      AO[(size_t)row * AO_COLS + col] = f2bf(opv[r2] * rowinv[quad*4 + r2]);
    }
  }
}

__global__ __launch_bounds__(512, 4) void attn_k(
    const unsigned short* __restrict__ Qb, const unsigned short* __restrict__ Kb,
    const unsigned short* __restrict__ Vt, unsigned short* __restrict__ AO,
    const float* __restrict__ WoF, unsigned short* __restrict__ Wob)
{
  __shared__ float S[16][SROW];                // 66,688 B (P bf16 overlays)
  __shared__ unsigned hist[8][256];            // 8192 B (64 bins x 4 replicas)
  __shared__ float rowinv[16];
  const int bid = (int)blockIdx.x;
  if (bid >= 2048) {
    // Wo convert: 512 threads x 8 elems = 4096 per block; blocks 2048..6143
    const size_t i = ((size_t)(bid - 2048) * 512 + threadIdx.x) * 8;
    float4 a = *(const float4*)(WoF + i);
    float4 c = *(const float4*)(WoF + i + 4);
    *(short8*)(Wob + i) = pack8(a, c);
    return;
  }
  const int bx = bid & 63;
  const int h = bid >> 6;
  const int rb = 63 - bx;                      // heavy blocks first
  const int kvh = h >> 2;                      // GROUPS=4
  const int q0 = rb * 16;
  const int kt_max = (rb >> 3) + 1;            // == (q0+16+127)>>7
  const int t = threadIdx.x, w = t >> 6, lane = t & 63;
  const int mcol = lane & 15, quad = lane >> 4;
  const unsigned short* Kh = Kb + (size_t)kvh * HEAD_STRIDE;  // [s][d]
  const unsigned short* Vh = Vt + (size_t)kvh * HEAD_STRIDE;  // [d][s]

  switch (kt_max) {
    case 1: attn_body<1>(Qb, Kh, Vh, AO, S, hist, rowinv, q0, h, w, lane, mcol, quad); break;
    case 2: attn_body<2>(Qb, Kh, Vh, AO, S, hist, rowinv, q0, h, w, lane, mcol, quad); break;
    case 3: attn_body<3>(Qb, Kh, Vh, AO, S, hist, rowinv, q0, h, w, lane, mcol, quad); break;
    case 4: attn_body<4>(Qb, Kh, Vh, AO, S, hist, rowinv, q0, h, w, lane, mcol, quad); break;
    case 5: attn_body<5>(Qb, Kh, Vh, AO, S, hist, rowinv, q0, h, w, lane, mcol, quad); break;
    case 6: attn_body<6>(Qb, Kh, Vh, AO, S, hist, rowinv, q0, h, w, lane, mcol, quad); break;
    case 7: attn_body<7>(Qb, Kh, Vh, AO, S, hist, rowinv, q0, h, w, lane, mcol, quad); break;
    default: attn_body<8>(Qb, Kh, Vh, AO, S, hist, rowinv, q0, h, w, lane, mcol, quad); break;
  }
}

// ---------------------------------------------------------------------------
// Kernel 4: output projection, 128x128 tiles, SPLIT-K=2 (grid (32,8,2) = 512
// blocks = 2/CU). Each z computes K half [z*2048,(z+1)*2048) and atomicAdd's
// f32 partials into the pre-zeroed Out. 2-way split => negligible rounding.
// ---------------------------------------------------------------------------
__global__ __launch_bounds__(256) void gemm_out_k(
    const unsigned short* __restrict__ A, const unsigned short* __restrict__ Wob,
    float* __restrict__ Out)
{
  __shared__ unsigned short As[3][128 * 32];
  __shared__ unsigned short Bs[3][128 * 32];
  const int n0 = blockIdx.x * 128;
  const int m0 = blockIdx.y * 128;
  const int kbase = blockIdx.z * 2048;
  const int t = threadIdx.x, w = t >> 6, lane = t & 63;
  const int wm = w >> 1, wn = w & 1;
  const int mcol = lane & 15, quad = lane >> 4;
  const int lrow = lane >> 2, lcol = (lane & 3) * 8;

  const unsigned short* Ag = A   + (size_t)m0 * AO_COLS + kbase;
  const unsigned short* Bg = Wob + (size_t)n0 * AO_COLS + kbase;

  f32x4 acc[4][4];
  #pragma unroll
  for (int i = 0; i < 4; i++)
    #pragma unroll
    for (int j = 0; j < 4; j++) acc[i][j] = (f32x4){0.f, 0.f, 0.f, 0.f};

  constexpr int NT = 2048 / 32;            // 64 K-tiles per split
  #define STAGE_OUT(buf, k0)                                                  \
    { const int c0 = w * 2, c1 = w * 2 + 1;                                   \
      gload_lds16(Ag + (size_t)(c0*16 + lrow) * AO_COLS + (k0) + lcol, &As[buf][c0 * 512]); \
      gload_lds16(Bg + (size_t)(c0*16 + lrow) * AO_COLS + (k0) + lcol, &Bs[buf][c0 * 512]); \
      gload_lds16(Ag + (size_t)(c1*16 + lrow) * AO_COLS + (k0) + lcol, &As[buf][c1 * 512]); \
      gload_lds16(Bg + (size_t)(c1*16 + lrow) * AO_COLS + (k0) + lcol, &Bs[buf][c1 * 512]); }

  STAGE_OUT(0, 0)
  STAGE_OUT(1, 32)
  asm volatile("s_waitcnt vmcnt(4)" ::: "memory");
  __builtin_amdgcn_s_barrier();
  __builtin_amdgcn_sched_barrier(0);

  int cur = 0, stg = 2;
  for (int kt = 0; kt < NT; ++kt) {
    if (kt + 2 < NT) STAGE_OUT(stg, (kt + 2) * 32)
    short8 af[4], bf[4];
    #pragma unroll
    for (int i = 0; i < 4; i++) af[i] = *(const short8*)&As[cur][(wm*64 + i*16 + mcol)*32 + quad*8];
    #pragma unroll
    for (int j = 0; j < 4; j++) bf[j] = *(const short8*)&Bs[cur][(wn*64 + j*16 + mcol)*32 + quad*8];
    #pragma unroll
    for (int i = 0; i < 4; i++)
      #pragma unroll
      for (int j = 0; j < 4; j++)
        acc[i][j] = __builtin_amdgcn_mfma_f32_16x16x32_bf16(af[i], bf[j], acc[i][j], 0, 0, 0);
    if (kt + 2 < NT) { asm volatile("s_waitcnt vmcnt(4)" ::: "memory"); }
    else             { asm volatile("s_waitcnt vmcnt(0)" ::: "memory"); }
    __builtin_amdgcn_s_barrier();
    __builtin_amdgcn_sched_barrier(0);
    cur = (cur == 2) ? 0 : cur + 1;
    stg = (stg == 2) ? 0 : stg + 1;
  }

  #pragma unroll
  for (int i = 0; i < 4; i++) {
    const int rb = m0 + wm*64 + i*16 + quad*4;
    #pragma unroll
    for (int j = 0; j < 4; j++) {
      const int col = n0 + wn*64 + j*16 + mcol;
      #pragma unroll
      for (int r = 0; r < 4; r++)
        atomicAdd(&Out[(size_t)(rb + r) * HID + col], acc[i][j][r]);
    }
  }
}

// ---------------------------------------------------------------------------
// Workspace layout (79,691,776 bytes total):
//   [0)          Qraw  bf16 [40][S][HD] (Q|K contiguous)   10,485,760
//   [+10485760)  Vt    bf16 [NKV][HD][S]                    2,097,152
//   [+12582912)  AO    bf16 [S][NH*HD]                      8,388,608
//   [+20971520)  Xb    bf16 [S][HID]                        8,388,608
//   [+29360128)  Wqkvb bf16 [6144][4096]                   50,331,648
//                Wob   bf16 [4096][4096] aliases Wqkvb (cvt during attn)
// ---------------------------------------------------------------------------
extern "C" void kernel_launch(void* const* d_in, const int* in_sizes, int n_in,
                              void* d_out, int out_size, void* d_ws, size_t ws_size,
                              hipStream_t stream) {
  (void)in_sizes; (void)n_in; (void)out_size; (void)ws_size;
  const float* X   = (const float*)d_in[0];
  const int*   pos = (const int*)d_in[1];
  const float* Wq  = (const float*)d_in[2];
  const float* Wk  = (const float*)d_in[3];
  const float* Wv  = (const float*)d_in[4];
  const float* Wo  = (const float*)d_in[5];
  float* out = (float*)d_out;

  char* ws = (char*)d_ws;
  unsigned short* Qraw  = (unsigned short*)ws;
  unsigned short* Kraw  = (unsigned short*)(ws + 8388608);    // = Qraw + 32 heads
  unsigned short* Vt    = (unsigned short*)(ws + 10485760);
  unsigned short* AO    = (unsigned short*)(ws + 12582912);
  unsigned short* Xb    = (unsigned short*)(ws + 20971520);
  unsigned short* Wqkvb = (unsigned short*)(ws + 29360128);
  unsigned short* Wob   = Wqkvb;   // alias: Wo converted during attn launch

  // bf16 conversions: X, Wq, Wk, Wv fused into one launch
  cvt4_k<<<dim3(14336), dim3(256), 0, stream>>>(X, Wq, Wk, Wv, Xb, Wqkvb);

  gemm_qkv_k<<<dim3(48, 8),  dim3(256), 0, stream>>>(Xb, Wqkvb, Qraw, Vt);
  rope_qk_k <<<dim3(10240),  dim3(256), 0, stream>>>(pos, Qraw);

  hipMemsetAsync(out, 0, (size_t)S_LEN * HID * sizeof(float), stream);

  // fused: attention (blocks 0..2047) + Wo convert (blocks 2048..6143)
  attn_k    <<<dim3(6144),   dim3(512), 0, stream>>>(Qraw, Kraw, Vt, AO, Wo, Wob);
  gemm_out_k<<<dim3(32, 8, 2), dim3(256), 0, stream>>>(AO, Wob, out);
}